// Round 2
// baseline (3289.032 us; speedup 1.0000x reference)
//
#include <hip/hip_runtime.h>
#include <hip/hip_bf16.h>

typedef __hip_bfloat16 bf16;

static constexpr int S   = 2048;
static constexpr int D   = 1024;
static constexpr int H   = 16;
static constexpr int DI  = 64;   // == DV
static constexpr int DFF = 4096;

__device__ __forceinline__ float ldin(const void* p, size_t i, bool bf) {
    return bf ? __bfloat162float(((const bf16*)p)[i]) : ((const float*)p)[i];
}
__device__ __forceinline__ void stout(void* p, size_t i, float v, bool bf) {
    if (bf) ((bf16*)p)[i] = __float2bfloat16(v);
    else    ((float*)p)[i] = v;
}

// ---------------------------------------------------------------------------
// Kernel 0: dtype detection. If input_vecs is bf16, low 16 bits of each 32-bit
// word are a plausible N(0,1) bf16 (exponent in [118,132]); if fp32, they are
// ~uniform mantissa bits (~6% hit rate). flags[0] = 1 for bf16, 0 for fp32.
// ---------------------------------------------------------------------------
__global__ void detect_kernel(const void* __restrict__ X, int* __restrict__ flags)
{
    const unsigned tid = threadIdx.x;
    const unsigned w  = ((const unsigned*)X)[tid];
    const unsigned lo = w & 0xFFFFu;
    const int e = (int)((lo >> 7) & 0xFF);
    const int ok = (e >= 118 && e <= 132) ? 1 : 0;
    __shared__ int cnt;
    if (tid == 0) cnt = 0;
    __syncthreads();
    atomicAdd(&cnt, ok);
    __syncthreads();
    if (tid == 0) flags[0] = (cnt >= 192) ? 1 : 0;
}

// ---------------------------------------------------------------------------
// Kernel 1: QKV projections.  grid = (S/64, H, 3), block = 256 (4x4/thread)
// ---------------------------------------------------------------------------
__global__ __launch_bounds__(256)
void qkv_kernel(const void* __restrict__ X,
                const void* __restrict__ WQ, const void* __restrict__ WK,
                const void* __restrict__ WV,
                float* __restrict__ Q, float* __restrict__ K, float* __restrict__ V,
                const int* __restrict__ flags)
{
    const bool bf = flags[0] != 0;
    const int h   = blockIdx.y;
    const int s0  = blockIdx.x * 64;
    const int sel = blockIdx.z;
    const void* W = (sel == 0) ? WQ : (sel == 1) ? WK : WV;
    float*      O = (sel == 0) ? Q  : (sel == 1) ? K  : V;

    __shared__ float As[64][17];
    __shared__ float Bs[16][65];

    const int tid = threadIdx.x;
    const int tx = tid & 15, ty = tid >> 4;
    float acc[4][4] = {};

    const int ar = tid >> 2;        // 0..63 (s row)
    const int ac = (tid & 3) * 4;   // 0,4,8,12 (k col)
    const int bk = tid >> 4;        // 0..15 (k row)
    const int be = (tid & 15) * 4;  // 0..60 (e col)

    for (int kt = 0; kt < D; kt += 16) {
        {
            const size_t base = (size_t)(s0 + ar) * D + kt + ac;
            As[ar][ac + 0] = ldin(X, base + 0, bf);
            As[ar][ac + 1] = ldin(X, base + 1, bf);
            As[ar][ac + 2] = ldin(X, base + 2, bf);
            As[ar][ac + 3] = ldin(X, base + 3, bf);
        }
        {
            const size_t base = ((size_t)h * D + kt + bk) * DI + be;
            Bs[bk][be + 0] = ldin(W, base + 0, bf);
            Bs[bk][be + 1] = ldin(W, base + 1, bf);
            Bs[bk][be + 2] = ldin(W, base + 2, bf);
            Bs[bk][be + 3] = ldin(W, base + 3, bf);
        }
        __syncthreads();
        #pragma unroll
        for (int kk = 0; kk < 16; ++kk) {
            float a[4], b[4];
            #pragma unroll
            for (int i = 0; i < 4; ++i) a[i] = As[ty * 4 + i][kk];
            #pragma unroll
            for (int j = 0; j < 4; ++j) b[j] = Bs[kk][tx * 4 + j];
            #pragma unroll
            for (int i = 0; i < 4; ++i)
                #pragma unroll
                for (int j = 0; j < 4; ++j)
                    acc[i][j] += a[i] * b[j];
        }
        __syncthreads();
    }
    #pragma unroll
    for (int i = 0; i < 4; ++i) {
        float* o = O + ((size_t)h * S + (s0 + ty * 4 + i)) * DI + tx * 4;
        o[0] = acc[i][0]; o[1] = acc[i][1]; o[2] = acc[i][2]; o[3] = acc[i][3];
    }
}

// ---------------------------------------------------------------------------
// Kernel 2: attention row.  grid = (S, H), block = 256.
// SA (flex dtype) goes to d_out; z -> zf fp32 [s][h*64+v]
// ---------------------------------------------------------------------------
__global__ __launch_bounds__(256)
void attn_kernel(const float* __restrict__ Q, const float* __restrict__ K,
                 const float* __restrict__ V, void* __restrict__ SA,
                 float* __restrict__ zf, const int* __restrict__ flags)
{
    const bool bf = flags[0] != 0;
    const int si  = blockIdx.x;
    const int h   = blockIdx.y;
    const int tid = threadIdx.x;

    __shared__ float ss[S];
    __shared__ float qs[64];
    __shared__ float red[256];
    __shared__ float zacc[4][64];

    const float slope = exp2f(-0.5f * (float)(h + 1));

    if (tid < 64) qs[tid] = Q[((size_t)h * S + si) * DI + tid];
    __syncthreads();

    float lmax = -INFINITY;
    for (int j = tid; j <= si; j += 256) {
        const float* kr = K + ((size_t)h * S + j) * DI;
        float dot = 0.f;
        #pragma unroll
        for (int d = 0; d < 64; d += 4) {
            float4 kv = *(const float4*)(kr + d);
            dot += qs[d] * kv.x + qs[d + 1] * kv.y + qs[d + 2] * kv.z + qs[d + 3] * kv.w;
        }
        float sc = dot * 0.125f - (float)(si - j) * slope;
        ss[j] = sc;
        lmax = fmaxf(lmax, sc);
    }
    red[tid] = lmax;
    __syncthreads();
    for (int off = 128; off > 0; off >>= 1) {
        if (tid < off) red[tid] = fmaxf(red[tid], red[tid + off]);
        __syncthreads();
    }
    const float m = red[0];
    __syncthreads();

    float lsum = 0.f;
    for (int j = tid; j <= si; j += 256) {
        float e = __expf(ss[j] - m);
        ss[j] = e;
        lsum += e;
    }
    red[tid] = lsum;
    __syncthreads();
    for (int off = 128; off > 0; off >>= 1) {
        if (tid < off) red[tid] += red[tid + off];
        __syncthreads();
    }
    const float inv = 1.f / red[0];

    const size_t rowbase = ((size_t)h * S + si) * S;
    for (int j = tid; j < S; j += 256) {
        float p = (j <= si) ? ss[j] * inv : 0.f;
        stout(SA, rowbase + j, p, bf);
    }

    const int g = tid >> 6, v = tid & 63;
    float a = 0.f;
    for (int j = g; j <= si; j += 4)
        a += ss[j] * V[((size_t)h * S + j) * DI + v];
    zacc[g][v] = a;
    __syncthreads();
    if (g == 0) {
        float z = (zacc[0][v] + zacc[1][v] + zacc[2][v] + zacc[3][v]) * inv;
        zf[(size_t)si * (H * DI) + h * DI + v] = z;
    }
}

// ---------------------------------------------------------------------------
// Kernel 3: C = A @ B^T (+bias)(+resid)(ReLU?), A fp32 [M,K], B flex [N,K].
// grid = (M/64, N/64), block = 256 (4x4/thread).
// ---------------------------------------------------------------------------
template <bool RESID_IN, bool RESID_WS, bool RELU, bool TO_DOUT>
__global__ __launch_bounds__(256)
void gemm_bt(const float* __restrict__ A, const void* __restrict__ B,
             const void* __restrict__ bias,
             const void* __restrict__ residIn, const float* __restrict__ residWs,
             float* __restrict__ Of, void* __restrict__ Od, size_t od_base,
             int M, int N, int Kd, const int* __restrict__ flags)
{
    const bool bf = flags[0] != 0;
    const int m0 = blockIdx.x * 64;
    const int n0 = blockIdx.y * 64;
    __shared__ float As[64][17];
    __shared__ float Bs[16][65];
    const int tid = threadIdx.x;
    const int tx = tid & 15, ty = tid >> 4;
    float acc[4][4] = {};

    const int r = tid >> 2;        // 0..63
    const int c = (tid & 3) * 4;   // 0,4,8,12

    for (int kt = 0; kt < Kd; kt += 16) {
        {
            const float4 av = *(const float4*)(A + (size_t)(m0 + r) * Kd + kt + c);
            As[r][c + 0] = av.x; As[r][c + 1] = av.y;
            As[r][c + 2] = av.z; As[r][c + 3] = av.w;
        }
        {
            const size_t base = (size_t)(n0 + r) * Kd + kt + c;
            Bs[c + 0][r] = ldin(B, base + 0, bf);
            Bs[c + 1][r] = ldin(B, base + 1, bf);
            Bs[c + 2][r] = ldin(B, base + 2, bf);
            Bs[c + 3][r] = ldin(B, base + 3, bf);
        }
        __syncthreads();
        #pragma unroll
        for (int kk = 0; kk < 16; ++kk) {
            float a[4], b[4];
            #pragma unroll
            for (int i = 0; i < 4; ++i) a[i] = As[ty * 4 + i][kk];
            #pragma unroll
            for (int j = 0; j < 4; ++j) b[j] = Bs[kk][tx * 4 + j];
            #pragma unroll
            for (int i = 0; i < 4; ++i)
                #pragma unroll
                for (int j = 0; j < 4; ++j)
                    acc[i][j] += a[i] * b[j];
        }
        __syncthreads();
    }
    #pragma unroll
    for (int i = 0; i < 4; ++i) {
        const int m = m0 + ty * 4 + i;
        #pragma unroll
        for (int j = 0; j < 4; ++j) {
            const int n = n0 + tx * 4 + j;
            float v = acc[i][j];
            v += ldin(bias, n, bf);
            if (RESID_IN) v += ldin(residIn, (size_t)m * N + n, bf);
            if (RESID_WS) v += residWs[(size_t)m * N + n];
            if (RELU)     v = fmaxf(v, 0.f);
            if (TO_DOUT) stout(Od, od_base + (size_t)m * N + n, v, bf);
            else         Of[(size_t)m * N + n] = v;
        }
    }
}

// ---------------------------------------------------------------------------
extern "C" void kernel_launch(void* const* d_in, const int* in_sizes, int n_in,
                              void* d_out, int out_size, void* d_ws, size_t ws_size,
                              hipStream_t stream)
{
    const void* X     = d_in[0];
    const void* WQs   = d_in[1];
    const void* WKs   = d_in[2];
    const void* WVs   = d_in[3];
    const void* WO_w  = d_in[4];
    const void* WO_b  = d_in[5];
    const void* FF1_w = d_in[6];
    const void* FF1_b = d_in[7];
    const void* FF2_w = d_in[8];
    const void* FF2_b = d_in[9];

    int*   flags = (int*)d_ws;
    float* fb    = (float*)d_ws + 64;

    const size_t HSD = (size_t)H * S * DI;   // 2,097,152
    float* Q   = fb;                  // [H,S,DI]
    float* K   = Q + HSD;
    float* V   = K + HSD;
    float* zf  = V + HSD;             // [S, H*DI]
    float* att = fb;                  // reuses Q slot (dead after attn)
    float* y1  = fb + HSD;            // reuses K/V/zf slots (dead after WO gemm)

    detect_kernel<<<1, 256, 0, stream>>>(X, flags);
    qkv_kernel<<<dim3(S / 64, H, 3), 256, 0, stream>>>(X, WQs, WKs, WVs, Q, K, V, flags);
    attn_kernel<<<dim3(S, H), 256, 0, stream>>>(Q, K, V, d_out, zf, flags);
    // att = X + zf @ WO_w^T + WO_b
    gemm_bt<true, false, false, false><<<dim3(S / 64, D / 64), 256, 0, stream>>>(
        zf, WO_w, WO_b, X, nullptr, att, nullptr, 0, S, D, D, flags);
    // y1 = relu(att @ FF1_w^T + FF1_b)
    gemm_bt<false, false, true, false><<<dim3(S / 64, DFF / 64), 256, 0, stream>>>(
        att, FF1_w, FF1_b, nullptr, nullptr, y1, nullptr, 0, S, DFF, D, flags);
    // out = att + y1 @ FF2_w^T + FF2_b  -> d_out (after SA)
    gemm_bt<false, true, false, true><<<dim3(S / 64, D / 64), 256, 0, stream>>>(
        y1, FF2_w, FF2_b, nullptr, att, nullptr, d_out, (size_t)H * S * S, S, D, DFF, flags);
}

// Round 3
// 609.110 us; speedup vs baseline: 5.3997x; 5.3997x over previous
//
#include <hip/hip_runtime.h>
#include <hip/hip_bf16.h>

typedef __hip_bfloat16 bf16;
typedef short v8s __attribute__((ext_vector_type(8)));   // 8 bf16 (4 VGPR) MFMA frag
typedef float f32x4 __attribute__((ext_vector_type(4))); // MFMA accumulator

static constexpr int S = 2048, D = 1024, H = 16, DFF = 4096;

__device__ __forceinline__ bf16  f2b(float x) { return __float2bfloat16(x); }
__device__ __forceinline__ float b2f(bf16 x)  { return __bfloat162float(x); }

// async 16B global -> LDS (wave-uniform LDS base + lane*16 layout)
__device__ __forceinline__ void gl2lds16(const void* g, void* l) {
    __builtin_amdgcn_global_load_lds(
        (const __attribute__((address_space(1))) unsigned int*)g,
        (__attribute__((address_space(3))) unsigned int*)l, 16, 0, 0);
}

// ---------------------------------------------------------------------------
// fp32 -> bf16 bulk convert: blockIdx.y selects segment {X, WO, FF1, FF2}
// ---------------------------------------------------------------------------
__global__ __launch_bounds__(256)
void cvt_all(const float* __restrict__ X, const float* __restrict__ WO,
             const float* __restrict__ F1, const float* __restrict__ F2,
             bf16* __restrict__ Xb, bf16* __restrict__ WOb,
             bf16* __restrict__ F1b, bf16* __restrict__ F2b)
{
    const float* src; bf16* dst; int n4;
    switch (blockIdx.y) {
        case 0:  src = X;  dst = Xb;  n4 = S * D / 4;   break;
        case 1:  src = WO; dst = WOb; n4 = D * D / 4;   break;
        case 2:  src = F1; dst = F1b; n4 = DFF * D / 4; break;
        default: src = F2; dst = F2b; n4 = D * DFF / 4; break;
    }
    const int i = blockIdx.x * 256 + threadIdx.x;
    if (i < n4) {
        const float4 v = ((const float4*)src)[i];
        bf16* p = dst + (size_t)i * 4;
        p[0] = f2b(v.x); p[1] = f2b(v.y); p[2] = f2b(v.z); p[3] = f2b(v.w);
    }
}

// ---------------------------------------------------------------------------
// Pack W{Q,K,V}[h][d][e] (fp32) -> Wcat[c][d] (bf16), c = sel*1024 + h*64 + e
// grid (16 dtiles, 16 h, 3 sel), block 256. LDS transpose.
// ---------------------------------------------------------------------------
__global__ __launch_bounds__(256)
void pack_w(const float* __restrict__ WQ, const float* __restrict__ WK,
            const float* __restrict__ WV, bf16* __restrict__ Wcat)
{
    const int d0 = blockIdx.x * 64, h = blockIdx.y, sel = blockIdx.z;
    const float* W = (sel == 0) ? WQ : (sel == 1) ? WK : WV;
    __shared__ float t[64][65];
    const int tid = threadIdx.x;
    for (int idx = tid; idx < 4096; idx += 256) {
        const int d = idx >> 6, e = idx & 63;
        t[d][e] = W[((size_t)h * D + d0 + d) * 64 + e];
    }
    __syncthreads();
    for (int idx = tid; idx < 4096; idx += 256) {
        const int e = idx >> 6, d = idx & 63;
        Wcat[(size_t)(sel * 1024 + h * 64 + e) * D + d0 + d] = f2b(t[d][e]);
    }
}

// ---------------------------------------------------------------------------
// NT GEMM: C[M,N] = A[M,K] * B[N,K]^T, bf16 MFMA 16x16x32, 128x128 tile, BK=32.
// 4 waves, each 64x64 (4x4 C-frags). global_load_lds 16B staging.
// EPI 0: QKV scatter; 1: +bias+X resid -> att_f/att_h; 2: +bias ReLU -> out_h;
// EPI 3: +bias+res_f -> out_f (d_out).
// ---------------------------------------------------------------------------
template<int EPI>
__global__ __launch_bounds__(256)
void gemm_nt(const bf16* __restrict__ A, const bf16* __restrict__ B,
             int M, int N, int K,
             const float* __restrict__ bias, const float* __restrict__ res_f,
             float* __restrict__ out_f, bf16* __restrict__ out_h,
             bf16* __restrict__ Qb, bf16* __restrict__ Kb, bf16* __restrict__ Vt)
{
    __shared__ bf16 sA[128 * 32];
    __shared__ bf16 sB[128 * 32];
    const int tid = threadIdx.x;
    const int lane = tid & 63, quad = lane >> 4, l15 = lane & 15;
    const int wave = tid >> 6, wm = wave >> 1, wn = wave & 1;
    const size_t m0 = (size_t)blockIdx.x * 128, n0 = (size_t)blockIdx.y * 128;
    const int trow = tid >> 2, tcol = (tid & 3) * 8;

    const bf16* pA = A + (m0 + trow) * (size_t)K + tcol;
    const bf16* pB = B + (n0 + trow) * (size_t)K + tcol;
    bf16* lA = sA + tid * 8;
    bf16* lB = sB + tid * 8;

    f32x4 acc[4][4] = {};

    for (int k0 = 0; k0 < K; k0 += 32) {
        gl2lds16(pA + k0, lA);
        gl2lds16(pA + 64 * (size_t)K + k0, lA + 2048);
        gl2lds16(pB + k0, lB);
        gl2lds16(pB + 64 * (size_t)K + k0, lB + 2048);
        __syncthreads();
        v8s af[4], bfr[4];
        #pragma unroll
        for (int t = 0; t < 4; ++t) {
            af[t]  = *(const v8s*)(sA + (wm * 64 + t * 16 + l15) * 32 + quad * 8);
            bfr[t] = *(const v8s*)(sB + (wn * 64 + t * 16 + l15) * 32 + quad * 8);
        }
        #pragma unroll
        for (int i = 0; i < 4; ++i)
            #pragma unroll
            for (int j = 0; j < 4; ++j)
                acc[i][j] = __builtin_amdgcn_mfma_f32_16x16x32_bf16(af[i], bfr[j], acc[i][j], 0, 0, 0);
        __syncthreads();
    }

    // epilogue (C layout: col = lane&15, row = quad*4 + reg)
    #pragma unroll
    for (int i = 0; i < 4; ++i) {
        const size_t mbase = m0 + wm * 64 + i * 16 + quad * 4;
        #pragma unroll
        for (int j = 0; j < 4; ++j) {
            const size_t n = n0 + wn * 64 + j * 16 + l15;
            if constexpr (EPI == 0) {
                const int sel = (int)(n >> 10), hh = (int)((n >> 6) & 15), e = (int)(n & 63);
                if (sel == 2) {
                    bf16* p = Vt + ((size_t)hh * 64 + e) * S + mbase;
                    p[0] = f2b(acc[i][j][0]); p[1] = f2b(acc[i][j][1]);
                    p[2] = f2b(acc[i][j][2]); p[3] = f2b(acc[i][j][3]);
                } else {
                    const float sc = (sel == 0) ? 0.125f : 1.0f;  // fold 1/sqrt(DI) into Q
                    bf16* p = ((sel == 0) ? Qb : Kb) + ((size_t)hh * S + mbase) * 64 + e;
                    p[0]   = f2b(acc[i][j][0] * sc);
                    p[64]  = f2b(acc[i][j][1] * sc);
                    p[128] = f2b(acc[i][j][2] * sc);
                    p[192] = f2b(acc[i][j][3] * sc);
                }
            } else {
                #pragma unroll
                for (int r = 0; r < 4; ++r) {
                    const size_t m = mbase + r;
                    float v = acc[i][j][r] + bias[n];
                    if constexpr (EPI == 1) {
                        v += res_f[m * (size_t)N + n];
                        out_f[m * (size_t)N + n] = v;
                        out_h[m * (size_t)N + n] = f2b(v);
                    }
                    if constexpr (EPI == 2) {
                        v = fmaxf(v, 0.f);
                        out_h[m * (size_t)N + n] = f2b(v);
                    }
                    if constexpr (EPI == 3) {
                        v += res_f[m * (size_t)N + n];
                        out_f[m * (size_t)N + n] = v;
                    }
                }
            }
        }
    }
}

// ---------------------------------------------------------------------------
// MFMA attention. grid (S/16, H), block 256 (4 waves).
// Q pre-scaled by 1/8. Softmax with shift c=0 (scores bounded ~15, safe).
// ebuf: unnormalized e (bf16) [16][2056] (pad -> conflict-lite PV reads).
// ---------------------------------------------------------------------------
__global__ __launch_bounds__(256)
void attn_kernel(const bf16* __restrict__ Qb, const bf16* __restrict__ Kb,
                 const bf16* __restrict__ Vt, float* __restrict__ SA,
                 bf16* __restrict__ zf)
{
    constexpr int EST = 2056;
    __shared__ bf16 ebuf[16 * EST];
    __shared__ float wsum[4][16];
    __shared__ float inv16[16];

    const int bi = blockIdx.x, h = blockIdx.y;
    const int i0 = bi * 16;
    const int tid = threadIdx.x, wave = tid >> 6, lane = tid & 63;
    const int quad = lane >> 4, l15 = lane & 15;
    const int ntiles = bi + 1;
    const float slope = exp2f(-0.5f * (float)(h + 1));

    // zero the PV overhang tile (odd ntiles reads 16 cols past the diag tile)
    { const int r = tid >> 4, c = ntiles * 16 + (tid & 15);
      if (c < EST) ebuf[r * EST + c] = f2b(0.f); }

    // Q fragments (A-layout: m = l15, k = quad*8 + r)
    const bf16* Qrow = Qb + ((size_t)h * S + i0 + l15) * 64;
    const v8s qf0 = *(const v8s*)(Qrow + quad * 8);
    const v8s qf1 = *(const v8s*)(Qrow + 32 + quad * 8);

    const bf16* Kh = Kb + (size_t)h * S * 64;
    float esum[4] = {0.f, 0.f, 0.f, 0.f};
    for (int jt = wave; jt < ntiles; jt += 4) {
        const bf16* Krow = Kh + (size_t)(jt * 16 + l15) * 64;
        const v8s kf0 = *(const v8s*)(Krow + quad * 8);
        const v8s kf1 = *(const v8s*)(Krow + 32 + quad * 8);
        f32x4 c = {0.f, 0.f, 0.f, 0.f};
        c = __builtin_amdgcn_mfma_f32_16x16x32_bf16(qf0, kf0, c, 0, 0, 0);
        c = __builtin_amdgcn_mfma_f32_16x16x32_bf16(qf1, kf1, c, 0, 0, 0);
        const int j = jt * 16 + l15;
        #pragma unroll
        for (int r = 0; r < 4; ++r) {
            const int i = i0 + quad * 4 + r;
            float e = 0.f;
            if (j <= i) e = __expf(c[r] - (float)(i - j) * slope);
            const bf16 eb = f2b(e);
            ebuf[(quad * 4 + r) * EST + j] = eb;
            esum[r] += b2f(eb);
        }
    }
    #pragma unroll
    for (int r = 0; r < 4; ++r) {
        float v = esum[r];
        v += __shfl_xor(v, 1); v += __shfl_xor(v, 2);
        v += __shfl_xor(v, 4); v += __shfl_xor(v, 8);
        if (l15 == 0) wsum[wave][quad * 4 + r] = v;
    }
    __syncthreads();
    if (tid < 16)
        inv16[tid] = 1.f / (wsum[0][tid] + wsum[1][tid] + wsum[2][tid] + wsum[3][tid]);
    __syncthreads();

    // SA rows (fp32, full width incl. zeros above diagonal)
    float* SAb = SA + ((size_t)h * S + i0) * S;
    for (int idx = tid; idx < 16 * 512; idx += 256) {
        const int row = idx >> 9, c4 = idx & 511;
        const int i = i0 + row, col = c4 * 4;
        const float iv = inv16[row];
        const bf16* er = ebuf + row * EST + col;
        float4 o;
        o.x = (col     <= i) ? b2f(er[0]) * iv : 0.f;
        o.y = (col + 1 <= i) ? b2f(er[1]) * iv : 0.f;
        o.z = (col + 2 <= i) ? b2f(er[2]) * iv : 0.f;
        o.w = (col + 3 <= i) ? b2f(er[3]) * iv : 0.f;
        ((float4*)(SAb + (size_t)row * S))[c4] = o;
    }

    // PV: wave w owns v-tile w (16 cols), contraction over j in chunks of 32
    const int nc = (bi + 2) >> 1;
    const bf16* Vrow = Vt + ((size_t)h * 64 + wave * 16 + l15) * (size_t)S;
    f32x4 oc = {0.f, 0.f, 0.f, 0.f};
    for (int ch = 0; ch < nc; ++ch) {
        const v8s pf = *(const v8s*)(ebuf + l15 * EST + ch * 32 + quad * 8);
        const v8s vf = *(const v8s*)(Vrow + ch * 32 + quad * 8);
        oc = __builtin_amdgcn_mfma_f32_16x16x32_bf16(pf, vf, oc, 0, 0, 0);
    }
    #pragma unroll
    for (int r = 0; r < 4; ++r) {
        const int row = quad * 4 + r;
        zf[(size_t)(i0 + row) * (H * 64) + h * 64 + wave * 16 + l15] = f2b(oc[r] * inv16[row]);
    }
}

// ---------------------------------------------------------------------------
extern "C" void kernel_launch(void* const* d_in, const int* in_sizes, int n_in,
                              void* d_out, int out_size, void* d_ws, size_t ws_size,
                              hipStream_t stream)
{
    const float* X     = (const float*)d_in[0];
    const float* WQs   = (const float*)d_in[1];
    const float* WKs   = (const float*)d_in[2];
    const float* WVs   = (const float*)d_in[3];
    const float* WO_w  = (const float*)d_in[4];
    const float* WO_b  = (const float*)d_in[5];
    const float* FF1_w = (const float*)d_in[6];
    const float* FF1_b = (const float*)d_in[7];
    const float* FF2_w = (const float*)d_in[8];
    const float* FF2_b = (const float*)d_in[9];

    float* SA   = (float*)d_out;                  // [H,S,S] fp32
    float* out2 = SA + (size_t)H * S * S;         // [S,D]  fp32

    char* ws = (char*)d_ws;
    bf16* FF1b = (bf16*)(ws);                         // 8 MB  [4096][1024]
    bf16* FF2b = (bf16*)(ws + (size_t)( 8u << 20));   // 8 MB  [1024][4096]
    bf16* Xb   = (bf16*)(ws + (size_t)(16u << 20));   // 4 MB  [2048][1024]
    bf16* Wcat = (bf16*)(ws + (size_t)(20u << 20));   // 6 MB  [3072][1024]
    bf16* WOb  = (bf16*)(ws + (size_t)(26u << 20));   // 2 MB  [1024][1024]
    bf16* zf   = (bf16*)(ws + (size_t)(28u << 20));   // 4 MB  [2048][1024]
    bf16* y1   = (bf16*)(ws + (size_t)(16u << 20));   // 16 MB [2048][4096] (aliases Xb..zf, dead by then)
    bf16* Qb   = (bf16*)(ws + (size_t)(32u << 20));   // 4 MB  [16][2048][64]
    bf16* Kb   = (bf16*)(ws + (size_t)(36u << 20));   // 4 MB
    bf16* Vt   = (bf16*)(ws + (size_t)(40u << 20));   // 4 MB  [16][64][2048]
    float* attf = (float*)(ws + (size_t)(32u << 20)); // 8 MB  (aliases Qb/Kb, dead after attn)
    bf16*  atth = (bf16*)(ws + (size_t)(40u << 20));  // 4 MB  (aliases Vt)

    cvt_all<<<dim3(4096, 4), 256, 0, stream>>>(X, WO_w, FF1_w, FF2_w, Xb, WOb, FF1b, FF2b);
    pack_w<<<dim3(16, 16, 3), 256, 0, stream>>>(WQs, WKs, WVs, Wcat);
    // QKV: [2048,1024] x [3072,1024]^T -> Qb/Kb/Vt
    gemm_nt<0><<<dim3(16, 24), 256, 0, stream>>>(Xb, Wcat, S, 3072, D,
        nullptr, nullptr, nullptr, nullptr, Qb, Kb, Vt);
    attn_kernel<<<dim3(S / 16, H), 256, 0, stream>>>(Qb, Kb, Vt, SA, zf);
    // att = X + zf @ WO^T + b  -> attf (fp32) + atth (bf16)
    gemm_nt<1><<<dim3(16, 8), 256, 0, stream>>>(zf, WOb, S, D, D,
        WO_b, X, attf, atth, nullptr, nullptr, nullptr);
    // y1 = relu(att @ FF1^T + b) -> bf16
    gemm_nt<2><<<dim3(16, 32), 256, 0, stream>>>(atth, FF1b, S, DFF, D,
        FF1_b, nullptr, nullptr, y1, nullptr, nullptr, nullptr);
    // out = att + y1 @ FF2^T + b -> d_out (fp32)
    gemm_nt<3><<<dim3(16, 8), 256, 0, stream>>>(y1, FF2b, S, D, DFF,
        FF2_b, attf, out2, nullptr, nullptr, nullptr, nullptr);
}

// Round 4
// 549.764 us; speedup vs baseline: 5.9826x; 1.1079x over previous
//
#include <hip/hip_runtime.h>
#include <hip/hip_bf16.h>

typedef __hip_bfloat16 bf16;
typedef short v8s __attribute__((ext_vector_type(8)));   // 8 bf16 (4 VGPR) MFMA frag
typedef float f32x4 __attribute__((ext_vector_type(4))); // MFMA accumulator

static constexpr int S = 2048, D = 1024, H = 16, DFF = 4096;

__device__ __forceinline__ bf16  f2b(float x) { return __float2bfloat16(x); }
__device__ __forceinline__ float b2f(bf16 x)  { return __bfloat162float(x); }

__device__ __forceinline__ void gl2lds16(const void* g, void* l) {
    __builtin_amdgcn_global_load_lds(
        (const __attribute__((address_space(1))) unsigned int*)g,
        (__attribute__((address_space(3))) unsigned int*)l, 16, 0, 0);
}

// ---------------------------------------------------------------------------
// fp32 -> bf16 bulk convert: blockIdx.y selects segment {X, WO, FF1, FF2}
// ---------------------------------------------------------------------------
__global__ __launch_bounds__(256)
void cvt_all(const float* __restrict__ X, const float* __restrict__ WO,
             const float* __restrict__ F1, const float* __restrict__ F2,
             bf16* __restrict__ Xb, bf16* __restrict__ WOb,
             bf16* __restrict__ F1b, bf16* __restrict__ F2b)
{
    const float* src; bf16* dst; int n4;
    switch (blockIdx.y) {
        case 0:  src = X;  dst = Xb;  n4 = S * D / 4;   break;
        case 1:  src = WO; dst = WOb; n4 = D * D / 4;   break;
        case 2:  src = F1; dst = F1b; n4 = DFF * D / 4; break;
        default: src = F2; dst = F2b; n4 = D * DFF / 4; break;
    }
    const int i = blockIdx.x * 256 + threadIdx.x;
    if (i < n4) {
        const float4 v = ((const float4*)src)[i];
        bf16* p = dst + (size_t)i * 4;
        p[0] = f2b(v.x); p[1] = f2b(v.y); p[2] = f2b(v.z); p[3] = f2b(v.w);
    }
}

// ---------------------------------------------------------------------------
// Pack W{Q,K,V}[h][d][e] (fp32) -> Wcat[c][d] (bf16), c = sel*1024 + h*64 + e
// ---------------------------------------------------------------------------
__global__ __launch_bounds__(256)
void pack_w(const float* __restrict__ WQ, const float* __restrict__ WK,
            const float* __restrict__ WV, bf16* __restrict__ Wcat)
{
    const int d0 = blockIdx.x * 64, h = blockIdx.y, sel = blockIdx.z;
    const float* W = (sel == 0) ? WQ : (sel == 1) ? WK : WV;
    __shared__ float t[64][65];
    const int tid = threadIdx.x;
    for (int idx = tid; idx < 4096; idx += 256) {
        const int d = idx >> 6, e = idx & 63;
        t[d][e] = W[((size_t)h * D + d0 + d) * 64 + e];
    }
    __syncthreads();
    for (int idx = tid; idx < 4096; idx += 256) {
        const int e = idx >> 6, d = idx & 63;
        Wcat[(size_t)(sel * 1024 + h * 64 + e) * D + d0 + d] = f2b(t[d][e]);
    }
}

// ---------------------------------------------------------------------------
// NT GEMM: C[M,N] = A[M,K] * B[N,K]^T, 128x128 tile, BK=32, 4 waves.
// EPI 0: QKV scatter; 1: +bias +X resid -> attf/atth; 2: +bias ReLU -> out_h;
// EPI 4: raw partial fp32 -> out_f + z*M*N (split-K).
// Kstride = row stride of A/B; Kd = contraction depth per launch.
// ---------------------------------------------------------------------------
template<int EPI>
__global__ __launch_bounds__(256)
void gemm_nt(const bf16* __restrict__ A, const bf16* __restrict__ B,
             int M, int N, int Kd, int Kstride,
             const float* __restrict__ bias, const float* __restrict__ res_f,
             float* __restrict__ out_f, bf16* __restrict__ out_h,
             bf16* __restrict__ Qb, bf16* __restrict__ Kb, bf16* __restrict__ Vt)
{
    __shared__ bf16 sA[128 * 32];
    __shared__ bf16 sB[128 * 32];
    const int tid = threadIdx.x;
    const int lane = tid & 63, quad = lane >> 4, l15 = lane & 15;
    const int wave = tid >> 6, wm = wave >> 1, wn = wave & 1;
    const size_t m0 = (size_t)blockIdx.x * 128, n0 = (size_t)blockIdx.y * 128;
    const int koff = (EPI == 4) ? blockIdx.z * Kd : 0;
    const int trow = tid >> 2, tcol = (tid & 3) * 8;

    const bf16* pA = A + (m0 + trow) * (size_t)Kstride + koff + tcol;
    const bf16* pB = B + (n0 + trow) * (size_t)Kstride + koff + tcol;
    bf16* lA = sA + tid * 8;
    bf16* lB = sB + tid * 8;

    f32x4 acc[4][4] = {};

    for (int k0 = 0; k0 < Kd; k0 += 32) {
        gl2lds16(pA + k0, lA);
        gl2lds16(pA + 64 * (size_t)Kstride + k0, lA + 2048);
        gl2lds16(pB + k0, lB);
        gl2lds16(pB + 64 * (size_t)Kstride + k0, lB + 2048);
        __syncthreads();
        v8s af[4], bfr[4];
        #pragma unroll
        for (int t = 0; t < 4; ++t) {
            af[t]  = *(const v8s*)(sA + (wm * 64 + t * 16 + l15) * 32 + quad * 8);
            bfr[t] = *(const v8s*)(sB + (wn * 64 + t * 16 + l15) * 32 + quad * 8);
        }
        #pragma unroll
        for (int i = 0; i < 4; ++i)
            #pragma unroll
            for (int j = 0; j < 4; ++j)
                acc[i][j] = __builtin_amdgcn_mfma_f32_16x16x32_bf16(af[i], bfr[j], acc[i][j], 0, 0, 0);
        __syncthreads();
    }

    #pragma unroll
    for (int i = 0; i < 4; ++i) {
        const size_t mbase = m0 + wm * 64 + i * 16 + quad * 4;
        #pragma unroll
        for (int j = 0; j < 4; ++j) {
            const size_t n = n0 + wn * 64 + j * 16 + l15;
            if constexpr (EPI == 0) {
                const int sel = (int)(n >> 10), hh = (int)((n >> 6) & 15), e = (int)(n & 63);
                if (sel == 2) {
                    bf16* p = Vt + ((size_t)hh * 64 + e) * S + mbase;
                    p[0] = f2b(acc[i][j][0]); p[1] = f2b(acc[i][j][1]);
                    p[2] = f2b(acc[i][j][2]); p[3] = f2b(acc[i][j][3]);
                } else {
                    const float sc = (sel == 0) ? 0.125f : 1.0f;  // fold 1/sqrt(DI) into Q
                    bf16* p = ((sel == 0) ? Qb : Kb) + ((size_t)hh * S + mbase) * 64 + e;
                    p[0]   = f2b(acc[i][j][0] * sc);
                    p[64]  = f2b(acc[i][j][1] * sc);
                    p[128] = f2b(acc[i][j][2] * sc);
                    p[192] = f2b(acc[i][j][3] * sc);
                }
            } else if constexpr (EPI == 4) {
                float* po = out_f + (size_t)blockIdx.z * (size_t)M * N;
                #pragma unroll
                for (int r = 0; r < 4; ++r)
                    po[(mbase + r) * (size_t)N + n] = acc[i][j][r];
            } else {
                #pragma unroll
                for (int r = 0; r < 4; ++r) {
                    const size_t m = mbase + r;
                    float v = acc[i][j][r] + bias[n];
                    if constexpr (EPI == 1) {
                        v += res_f[m * (size_t)N + n];
                        out_f[m * (size_t)N + n] = v;
                        out_h[m * (size_t)N + n] = f2b(v);
                    }
                    if constexpr (EPI == 2) {
                        v = fmaxf(v, 0.f);
                        out_h[m * (size_t)N + n] = f2b(v);
                    }
                }
            }
        }
    }
}

// ---------------------------------------------------------------------------
// ff2 combine: out2 = p0 + p1 + bias + attf  (fp32, float4)
// ---------------------------------------------------------------------------
__global__ __launch_bounds__(256)
void ff2_combine(const float* __restrict__ p0, const float* __restrict__ p1,
                 const float* __restrict__ bias, const float* __restrict__ attf,
                 float* __restrict__ out2)
{
    const int i = blockIdx.x * 256 + threadIdx.x;       // float4 index
    const float4 a = ((const float4*)p0)[i];
    const float4 b = ((const float4*)p1)[i];
    const float4 r = ((const float4*)attf)[i];
    const float4 bs = ((const float4*)bias)[i & (D / 4 - 1)];
    float4 o;
    o.x = a.x + b.x + r.x + bs.x;
    o.y = a.y + b.y + r.y + bs.y;
    o.z = a.z + b.z + r.z + bs.z;
    o.w = a.w + b.w + r.w + bs.w;
    ((float4*)out2)[i] = o;
}

// ---------------------------------------------------------------------------
// MFMA attention. grid (S/16, H), block 512 (8 waves), heavy blocks first.
// ---------------------------------------------------------------------------
__global__ __launch_bounds__(512)
void attn_kernel(const bf16* __restrict__ Qb, const bf16* __restrict__ Kb,
                 const bf16* __restrict__ Vt, float* __restrict__ SA,
                 bf16* __restrict__ zf)
{
    constexpr int EST = 2056;
    __shared__ bf16 ebuf[16 * EST];          // 64.3 KB
    __shared__ float wsum[8][16];
    __shared__ float inv16[16];
    __shared__ float pvacc[8][16][16];       // 8 KB

    const int bi = (int)gridDim.x - 1 - (int)blockIdx.x;   // heavy first
    const int h = blockIdx.y;
    const int i0 = bi * 16;
    const int tid = threadIdx.x, wave = tid >> 6, lane = tid & 63;
    const int quad = lane >> 4, l15 = lane & 15;
    const int ntiles = bi + 1;
    const float slope = exp2f(-0.5f * (float)(h + 1));

    // zero the PV overhang tile (odd ntiles reads 16 cols past the diag tile)
    if (tid < 256) {
        const int r = tid >> 4, c = ntiles * 16 + (tid & 15);
        if (c < EST) ebuf[r * EST + c] = f2b(0.f);
    }

    // Q fragments (A-layout: m = l15, k = quad*8 + r)
    const bf16* Qrow = Qb + ((size_t)h * S + i0 + l15) * 64;
    const v8s qf0 = *(const v8s*)(Qrow + quad * 8);
    const v8s qf1 = *(const v8s*)(Qrow + 32 + quad * 8);

    const bf16* Kh = Kb + (size_t)h * S * 64;
    float esum[4] = {0.f, 0.f, 0.f, 0.f};
    {
        int jt = wave;
        v8s kf0 = {}, kf1 = {};
        if (jt < ntiles) {
            const bf16* Krow = Kh + (size_t)(jt * 16 + l15) * 64;
            kf0 = *(const v8s*)(Krow + quad * 8);
            kf1 = *(const v8s*)(Krow + 32 + quad * 8);
        }
        while (jt < ntiles) {
            const int jn = jt + 8;
            v8s nf0 = kf0, nf1 = kf1;
            if (jn < ntiles) {
                const bf16* Krow = Kh + (size_t)(jn * 16 + l15) * 64;
                nf0 = *(const v8s*)(Krow + quad * 8);
                nf1 = *(const v8s*)(Krow + 32 + quad * 8);
            }
            f32x4 c = {0.f, 0.f, 0.f, 0.f};
            c = __builtin_amdgcn_mfma_f32_16x16x32_bf16(qf0, kf0, c, 0, 0, 0);
            c = __builtin_amdgcn_mfma_f32_16x16x32_bf16(qf1, kf1, c, 0, 0, 0);
            const int j = jt * 16 + l15;
            #pragma unroll
            for (int r = 0; r < 4; ++r) {
                const int i = i0 + quad * 4 + r;
                float e = 0.f;
                if (j <= i) e = __expf(c[r] - (float)(i - j) * slope);
                const bf16 eb = f2b(e);
                ebuf[(quad * 4 + r) * EST + j] = eb;
                esum[r] += b2f(eb);
            }
            kf0 = nf0; kf1 = nf1; jt = jn;
        }
    }
    #pragma unroll
    for (int r = 0; r < 4; ++r) {
        float v = esum[r];
        v += __shfl_xor(v, 1); v += __shfl_xor(v, 2);
        v += __shfl_xor(v, 4); v += __shfl_xor(v, 8);
        if (l15 == 0) wsum[wave][quad * 4 + r] = v;
    }
    __syncthreads();
    if (tid < 16) {
        float s = 0.f;
        #pragma unroll
        for (int w = 0; w < 8; ++w) s += wsum[w][tid];
        inv16[tid] = 1.f / s;
    }
    __syncthreads();

    // SA rows (fp32, full width incl. zeros above diagonal)
    float* SAb = SA + ((size_t)h * S + i0) * S;
    for (int idx = tid; idx < 16 * 512; idx += 512) {
        const int row = idx >> 9, c4 = idx & 511;
        const int i = i0 + row, col = c4 * 4;
        const float iv = inv16[row];
        const bf16* er = ebuf + row * EST + col;
        float4 o;
        o.x = (col     <= i) ? b2f(er[0]) * iv : 0.f;
        o.y = (col + 1 <= i) ? b2f(er[1]) * iv : 0.f;
        o.z = (col + 2 <= i) ? b2f(er[2]) * iv : 0.f;
        o.w = (col + 3 <= i) ? b2f(er[3]) * iv : 0.f;
        ((float4*)(SAb + (size_t)row * S))[c4] = o;
    }

    // PV: vtile = wave&3 (16 v-cols), j-range split over wave>>2 (partials)
    const int nc = (bi + 2) >> 1;
    const int vt = wave & 3, jh = wave >> 2;
    const bf16* Vrow = Vt + ((size_t)h * 64 + vt * 16 + l15) * (size_t)S;
    f32x4 oc = {0.f, 0.f, 0.f, 0.f};
    {
        int ch = jh;
        v8s vf = {};
        if (ch < nc) vf = *(const v8s*)(Vrow + ch * 32 + quad * 8);
        while (ch < nc) {
            const int cn = ch + 2;
            v8s vn = vf;
            if (cn < nc) vn = *(const v8s*)(Vrow + cn * 32 + quad * 8);
            const v8s pf = *(const v8s*)(ebuf + l15 * EST + ch * 32 + quad * 8);
            oc = __builtin_amdgcn_mfma_f32_16x16x32_bf16(pf, vf, oc, 0, 0, 0);
            vf = vn; ch = cn;
        }
    }
    #pragma unroll
    for (int r = 0; r < 4; ++r)
        pvacc[wave][quad * 4 + r][l15] = oc[r];
    __syncthreads();
    // combine wave pairs (w, w+4), scale, write zf
    for (int idx = tid; idx < 1024; idx += 512) {
        const int v4 = idx >> 8, rem = idx & 255, row = rem >> 4, col = rem & 15;
        const float z = (pvacc[v4][row][col] + pvacc[v4 + 4][row][col]) * inv16[row];
        zf[(size_t)(i0 + row) * (H * 64) + h * 64 + v4 * 16 + col] = f2b(z);
    }
}

// ---------------------------------------------------------------------------
extern "C" void kernel_launch(void* const* d_in, const int* in_sizes, int n_in,
                              void* d_out, int out_size, void* d_ws, size_t ws_size,
                              hipStream_t stream)
{
    const float* X     = (const float*)d_in[0];
    const float* WQs   = (const float*)d_in[1];
    const float* WKs   = (const float*)d_in[2];
    const float* WVs   = (const float*)d_in[3];
    const float* WO_w  = (const float*)d_in[4];
    const float* WO_b  = (const float*)d_in[5];
    const float* FF1_w = (const float*)d_in[6];
    const float* FF1_b = (const float*)d_in[7];
    const float* FF2_w = (const float*)d_in[8];
    const float* FF2_b = (const float*)d_in[9];

    float* SA   = (float*)d_out;                  // [H,S,S] fp32
    float* out2 = SA + (size_t)H * S * S;         // [S,D]  fp32

    char* ws = (char*)d_ws;
    const size_t MB = 1u << 20;
    bf16*  FF1b = (bf16*)(ws);            // 8 MB [4096][1024]
    bf16*  FF2b = (bf16*)(ws + 8 * MB);   // 8 MB [1024][4096]
    bf16*  Xb   = (bf16*)(ws + 16 * MB);  // 4 MB [2048][1024]
    bf16*  Wcat = (bf16*)(ws + 20 * MB);  // 6 MB [3072][1024]
    bf16*  WOb  = (bf16*)(ws + 26 * MB);  // 2 MB [1024][1024]
    bf16*  zf   = (bf16*)(ws + 28 * MB);  // 4 MB [2048][1024]
    bf16*  Qb   = (bf16*)(ws + 32 * MB);  // 4 MB [16][2048][64]
    bf16*  Kb   = (bf16*)(ws + 36 * MB);  // 4 MB
    bf16*  Vt   = (bf16*)(ws + 40 * MB);  // 4 MB [16][64][2048]
    float* attf = (float*)(ws + 44 * MB); // 8 MB [2048][1024]
    bf16*  atth = (bf16*)(ws + 52 * MB);  // 4 MB
    bf16*  y1   = (bf16*)(ws + 56 * MB);  // 16 MB [2048][4096]
    float* p0   = (float*)(ws + 72 * MB); // 8.4 MB (split-K partial 0; p1 at +9MB)

    cvt_all<<<dim3(4096, 4), 256, 0, stream>>>(X, WO_w, FF1_w, FF2_w, Xb, WOb, FF1b, FF2b);
    pack_w<<<dim3(16, 16, 3), 256, 0, stream>>>(WQs, WKs, WVs, Wcat);
    gemm_nt<0><<<dim3(16, 24), 256, 0, stream>>>(Xb, Wcat, S, 3072, D, D,
        nullptr, nullptr, nullptr, nullptr, Qb, Kb, Vt);
    attn_kernel<<<dim3(S / 16, H), 512, 0, stream>>>(Qb, Kb, Vt, SA, zf);
    gemm_nt<1><<<dim3(16, 8), 256, 0, stream>>>(zf, WOb, S, D, D, D,
        WO_b, X, attf, atth, nullptr, nullptr, nullptr);
    gemm_nt<2><<<dim3(16, 32), 256, 0, stream>>>(atth, FF1b, S, DFF, D, D,
        FF1_b, nullptr, nullptr, y1, nullptr, nullptr, nullptr);
    gemm_nt<4><<<dim3(16, 8, 2), 256, 0, stream>>>(y1, FF2b, S, D, DFF / 2, DFF,
        nullptr, nullptr, p0, nullptr, nullptr, nullptr, nullptr);
    ff2_combine<<<dim3(S * D / 4 / 256), 256, 0, stream>>>(
        p0, p0 + (size_t)S * D, FF2_b, attf, out2);
}